// Round 1
// baseline (510.958 us; speedup 1.0000x reference)
//
#include <hip/hip_runtime.h>
#include <math.h>

#define N_NODES 4096
#define DEG 16
#define DIM 64
#define HID 128
#define KCAT 2048   // DEG*2*DIM

// ---------------------------------------------------------------------------
// Kernel 1: vproj[side][n][h] = sum_k cv[n][k] * W[k][h]
// cv[n] = concat over d of [A[adjA[n,d]] (64), B[adjB[n,d]] (64)]
// side 0: A=review(adj0), B=item(adj1), W=user_weights
// side 1: A=review(adj2), B=user(adj3), W=item_weights
// ---------------------------------------------------------------------------
#define NPB 8   // nodes per block
__global__ __launch_bounds__(256)
void gather_project(const float* __restrict__ review,
                    const float* __restrict__ userv,
                    const float* __restrict__ itemv,
                    const float* __restrict__ uW,
                    const float* __restrict__ iW,
                    const int* __restrict__ adj0,
                    const int* __restrict__ adj1,
                    const int* __restrict__ adj2,
                    const int* __restrict__ adj3,
                    float* __restrict__ vproj)
{
    const int side = blockIdx.x >> 9;          // 512 blocks per side
    const int nb   = blockIdx.x & 511;
    const int* __restrict__ adjA = side ? adj2 : adj0;
    const int* __restrict__ adjB = side ? adj3 : adj1;
    const float* __restrict__ A = review;
    const float* __restrict__ B = side ? userv : itemv;
    const float* __restrict__ W = side ? iW : uW;
    float* __restrict__ out = vproj + (size_t)side * N_NODES * HID;

    __shared__ __align__(16) float cv[NPB][KCAT];   // 64 KB
    const int t = threadIdx.x;

    // Gather: NPB*2048 floats = 4096 float4, 16 per thread.
    for (int e4 = t; e4 < NPB * (KCAT / 4); e4 += 256) {
        int i    = e4 >> 9;        // node within block (512 f4 per node)
        int rem  = e4 & 511;
        int d    = rem >> 5;       // 32 f4 per deg slot
        int j4   = rem & 31;
        int node = nb * NPB + i;
        float4 v;
        if (j4 < 16) {
            int idx = adjA[node * DEG + d];
            v = *(const float4*)(A + (size_t)idx * DIM + j4 * 4);
        } else {
            int idx = adjB[node * DEG + d];
            v = *(const float4*)(B + (size_t)idx * DIM + (j4 - 16) * 4);
        }
        *(float4*)&cv[i][d * 128 + j4 * 4] = v;
    }
    __syncthreads();

    const int h = t & 127;
    const int g = t >> 7;   // 0..1 -> nodes g*4 .. g*4+3
    float acc0 = 0.f, acc1 = 0.f, acc2 = 0.f, acc3 = 0.f;
    for (int k = 0; k < KCAT; k += 4) {
        float w0 = W[(k + 0) * HID + h];
        float w1 = W[(k + 1) * HID + h];
        float w2 = W[(k + 2) * HID + h];
        float w3 = W[(k + 3) * HID + h];
        float4 c0 = *(const float4*)&cv[g * 4 + 0][k];
        float4 c1 = *(const float4*)&cv[g * 4 + 1][k];
        float4 c2 = *(const float4*)&cv[g * 4 + 2][k];
        float4 c3 = *(const float4*)&cv[g * 4 + 3][k];
        acc0 += c0.x * w0 + c0.y * w1 + c0.z * w2 + c0.w * w3;
        acc1 += c1.x * w0 + c1.y * w1 + c1.z * w2 + c1.w * w3;
        acc2 += c2.x * w0 + c2.y * w1 + c2.z * w2 + c2.w * w3;
        acc3 += c3.x * w0 + c3.y * w1 + c3.z * w2 + c3.w * w3;
    }
    out[(size_t)(nb * NPB + g * 4 + 0) * HID + h] = acc0;
    out[(size_t)(nb * NPB + g * 4 + 1) * HID + h] = acc1;
    out[(size_t)(nb * NPB + g * 4 + 2) * HID + h] = acc2;
    out[(size_t)(nb * NPB + g * 4 + 3) * HID + h] = acc3;
}

// ---------------------------------------------------------------------------
// Kernel 2: fused flash attention.
// out[n] = relu( softmax(X X^T / 8)[n] @ vproj )   per side.
// QT=16 queries per block, key tiles of KT=64.
// ---------------------------------------------------------------------------
#define QT 16
#define KT 64

__global__ __launch_bounds__(256)
void flash_attn(const float* __restrict__ userv,
                const float* __restrict__ itemv,
                const float* __restrict__ vproj,
                float* __restrict__ outp)
{
    const int side = blockIdx.x >> 8;   // 256 q-blocks per side
    const int qb   = blockIdx.x & 255;
    const float* __restrict__ X = side ? itemv : userv;  // q == k matrix
    const float* __restrict__ V = vproj + (size_t)side * N_NODES * HID;
    float* __restrict__ O = outp + (size_t)side * N_NODES * HID;

    __shared__ __align__(16) float Qs[QT][68];    // padded rows, 16B-aligned
    __shared__ __align__(16) float KsT[DIM][68];  // [kk][k]: transposed K tile
    __shared__ __align__(16) float Vs[KT][HID];
    __shared__ __align__(16) float psT[KT][20];   // [k][q]
    __shared__ float mrun[QT], lrun[QT], rs[QT];

    const int t = threadIdx.x;

    // Load Q tile (one float4 per thread).
    {
        int q = t >> 4, c4 = t & 15;
        *(float4*)&Qs[q][c4 * 4] =
            *(const float4*)(X + (size_t)(qb * QT + q) * DIM + c4 * 4);
    }
    if (t < QT) { mrun[t] = -INFINITY; lrun[t] = 0.f; }

    float4 o0 = {0.f, 0.f, 0.f, 0.f};
    float4 o1 = {0.f, 0.f, 0.f, 0.f};

    const int h4 = t & 31, qg = t >> 5;   // PV mapping: h = h4*4.., q = qg*2..
    const int qS = t >> 4, k4 = t & 15;   // S / softmax mapping

    for (int kt = 0; kt < N_NODES / KT; ++kt) {
        const int k0 = kt * KT;
        __syncthreads();   // prev tile fully consumed

        // Load K tile transposed: KsT[kk][k] = X[k0+k][kk]
        #pragma unroll
        for (int it = 0; it < 4; ++it) {
            int idx = t + 256 * it;        // 1024 float4
            int row = idx >> 4, c = idx & 15;
            float4 kv = *(const float4*)(X + (size_t)(k0 + row) * DIM + c * 4);
            KsT[c * 4 + 0][row] = kv.x;
            KsT[c * 4 + 1][row] = kv.y;
            KsT[c * 4 + 2][row] = kv.z;
            KsT[c * 4 + 3][row] = kv.w;
        }
        // Load V tile linear.
        #pragma unroll
        for (int it = 0; it < 8; ++it) {
            int idx = t + 256 * it;        // 2048 float4
            int row = idx >> 5, c = idx & 31;
            *(float4*)&Vs[row][c * 4] =
                *(const float4*)(V + (size_t)(k0 + row) * HID + c * 4);
        }
        __syncthreads();

        // S-step: 4 dots per thread -> psT[k][q] (scaled)
        {
            float s0 = 0.f, s1 = 0.f, s2 = 0.f, s3 = 0.f;
            for (int kk = 0; kk < DIM; ++kk) {
                float qv = Qs[qS][kk];
                float4 kv = *(const float4*)&KsT[kk][k4 * 4];
                s0 += qv * kv.x; s1 += qv * kv.y;
                s2 += qv * kv.z; s3 += qv * kv.w;
            }
            psT[k4 * 4 + 0][qS] = s0 * 0.125f;
            psT[k4 * 4 + 1][qS] = s1 * 0.125f;
            psT[k4 * 4 + 2][qS] = s2 * 0.125f;
            psT[k4 * 4 + 3][qS] = s3 * 0.125f;
        }
        __syncthreads();

        // Online softmax over this tile's 64 keys (16 lanes per query).
        {
            float s0 = psT[k4 * 4 + 0][qS];
            float s1 = psT[k4 * 4 + 1][qS];
            float s2 = psT[k4 * 4 + 2][qS];
            float s3 = psT[k4 * 4 + 3][qS];
            float mx = fmaxf(fmaxf(s0, s1), fmaxf(s2, s3));
            #pragma unroll
            for (int off = 8; off; off >>= 1)
                mx = fmaxf(mx, __shfl_xor(mx, off, 16));
            float mold = mrun[qS];
            float mnew = fmaxf(mold, mx);
            float r = __expf(mold - mnew);          // 0 on first tile
            float p0 = __expf(s0 - mnew);
            float p1 = __expf(s1 - mnew);
            float p2 = __expf(s2 - mnew);
            float p3 = __expf(s3 - mnew);
            psT[k4 * 4 + 0][qS] = p0;
            psT[k4 * 4 + 1][qS] = p1;
            psT[k4 * 4 + 2][qS] = p2;
            psT[k4 * 4 + 3][qS] = p3;
            float ps = p0 + p1 + p2 + p3;
            #pragma unroll
            for (int off = 8; off; off >>= 1)
                ps += __shfl_xor(ps, off, 16);
            if (k4 == 0) {
                mrun[qS] = mnew;
                lrun[qS] = lrun[qS] * r + ps;
                rs[qS]   = r;
            }
        }
        __syncthreads();

        // PV: o[q][h] = o*r + sum_k p[k][q] * V[k][h]
        {
            float r0 = rs[qg * 2 + 0];
            float r1 = rs[qg * 2 + 1];
            o0.x *= r0; o0.y *= r0; o0.z *= r0; o0.w *= r0;
            o1.x *= r1; o1.y *= r1; o1.z *= r1; o1.w *= r1;
            for (int k = 0; k < KT; ++k) {
                float4 v = *(const float4*)&Vs[k][h4 * 4];
                float2 p = *(const float2*)&psT[k][qg * 2];
                o0.x += p.x * v.x; o0.y += p.x * v.y;
                o0.z += p.x * v.z; o0.w += p.x * v.w;
                o1.x += p.y * v.x; o1.y += p.y * v.y;
                o1.z += p.y * v.z; o1.w += p.y * v.w;
            }
        }
    }

    // Epilogue: divide by l, relu, store.
    {
        float li0 = 1.0f / lrun[qg * 2 + 0];
        float li1 = 1.0f / lrun[qg * 2 + 1];
        float4 r0, r1;
        r0.x = fmaxf(o0.x * li0, 0.f); r0.y = fmaxf(o0.y * li0, 0.f);
        r0.z = fmaxf(o0.z * li0, 0.f); r0.w = fmaxf(o0.w * li0, 0.f);
        r1.x = fmaxf(o1.x * li1, 0.f); r1.y = fmaxf(o1.y * li1, 0.f);
        r1.z = fmaxf(o1.z * li1, 0.f); r1.w = fmaxf(o1.w * li1, 0.f);
        int q0 = qb * QT + qg * 2;
        *(float4*)(O + (size_t)(q0 + 0) * HID + h4 * 4) = r0;
        *(float4*)(O + (size_t)(q0 + 1) * HID + h4 * 4) = r1;
    }
}

// ---------------------------------------------------------------------------
extern "C" void kernel_launch(void* const* d_in, const int* in_sizes, int n_in,
                              void* d_out, int out_size, void* d_ws, size_t ws_size,
                              hipStream_t stream)
{
    const float* review = (const float*)d_in[0];
    const float* userv  = (const float*)d_in[1];
    const float* itemv  = (const float*)d_in[2];
    const float* uW     = (const float*)d_in[3];
    const float* iW     = (const float*)d_in[4];
    const int*   adj0   = (const int*)d_in[5];
    const int*   adj1   = (const int*)d_in[6];
    const int*   adj2   = (const int*)d_in[7];
    const int*   adj3   = (const int*)d_in[8];
    float* out   = (float*)d_out;
    float* vproj = (float*)d_ws;   // 2 * 4096 * 128 * 4B = 4 MB

    gather_project<<<1024, 256, 0, stream>>>(review, userv, itemv, uW, iW,
                                             adj0, adj1, adj2, adj3, vproj);
    flash_attn<<<512, 256, 0, stream>>>(userv, itemv, vproj, out);
}

// Round 2
// 315.169 us; speedup vs baseline: 1.6212x; 1.6212x over previous
//
#include <hip/hip_runtime.h>
#include <hip/hip_bf16.h>
#include <math.h>

#define N_NODES 4096
#define DEG 16
#define DIM 64
#define HID 128
#define KCAT 2048   // DEG*2*DIM

typedef __attribute__((ext_vector_type(8))) short bf16x8;
typedef __attribute__((ext_vector_type(4))) float f32x4;

static __device__ __forceinline__ unsigned pk2(float a, float b) {
    __hip_bfloat162 h = __float22bfloat162_rn(make_float2(a, b));
    return *reinterpret_cast<unsigned*>(&h);
}

// ---------------------------------------------------------------------------
// Kernel 1: vprojT[side][h][n] = bf16( sum_k cv[n][k] * W[k][h] )
// cv[n] = concat over d of [A[adjA[n,d]] (64), B[adjB[n,d]] (64)]
// f32 VALU compute (MFMA-ize next round); output transposed bf16 for kernel 2.
// ---------------------------------------------------------------------------
#define NPB 8   // nodes per block
__global__ __launch_bounds__(256)
void gather_project(const float* __restrict__ review,
                    const float* __restrict__ userv,
                    const float* __restrict__ itemv,
                    const float* __restrict__ uW,
                    const float* __restrict__ iW,
                    const int* __restrict__ adj0,
                    const int* __restrict__ adj1,
                    const int* __restrict__ adj2,
                    const int* __restrict__ adj3,
                    ushort* __restrict__ vprojT)
{
    const int side = blockIdx.x >> 9;          // 512 blocks per side
    const int nb   = blockIdx.x & 511;
    const int* __restrict__ adjA = side ? adj2 : adj0;
    const int* __restrict__ adjB = side ? adj3 : adj1;
    const float* __restrict__ A = review;
    const float* __restrict__ B = side ? userv : itemv;
    const float* __restrict__ W = side ? iW : uW;
    ushort* __restrict__ outT = vprojT + (size_t)side * HID * N_NODES;

    __shared__ __align__(16) float cv[NPB][KCAT];   // 64 KB
    const int t = threadIdx.x;

    for (int e4 = t; e4 < NPB * (KCAT / 4); e4 += 256) {
        int i    = e4 >> 9;
        int rem  = e4 & 511;
        int d    = rem >> 5;
        int j4   = rem & 31;
        int node = nb * NPB + i;
        float4 v;
        if (j4 < 16) {
            int idx = adjA[node * DEG + d];
            v = *(const float4*)(A + (size_t)idx * DIM + j4 * 4);
        } else {
            int idx = adjB[node * DEG + d];
            v = *(const float4*)(B + (size_t)idx * DIM + (j4 - 16) * 4);
        }
        *(float4*)&cv[i][d * 128 + j4 * 4] = v;
    }
    __syncthreads();

    const int h = t & 127;
    const int g = t >> 7;   // 0..1 -> nodes g*4 .. g*4+3
    float acc0 = 0.f, acc1 = 0.f, acc2 = 0.f, acc3 = 0.f;
    for (int k = 0; k < KCAT; k += 4) {
        float w0 = W[(k + 0) * HID + h];
        float w1 = W[(k + 1) * HID + h];
        float w2 = W[(k + 2) * HID + h];
        float w3 = W[(k + 3) * HID + h];
        float4 c0 = *(const float4*)&cv[g * 4 + 0][k];
        float4 c1 = *(const float4*)&cv[g * 4 + 1][k];
        float4 c2 = *(const float4*)&cv[g * 4 + 2][k];
        float4 c3 = *(const float4*)&cv[g * 4 + 3][k];
        acc0 += c0.x * w0 + c0.y * w1 + c0.z * w2 + c0.w * w3;
        acc1 += c1.x * w0 + c1.y * w1 + c1.z * w2 + c1.w * w3;
        acc2 += c2.x * w0 + c2.y * w1 + c2.z * w2 + c2.w * w3;
        acc3 += c3.x * w0 + c3.y * w1 + c3.z * w2 + c3.w * w3;
    }
    // transposed bf16 store: 4 consecutive n -> one 8B store
    uint2 pk;
    pk.x = pk2(acc0, acc1);
    pk.y = pk2(acc2, acc3);
    *(uint2*)(outT + (size_t)h * N_NODES + nb * NPB + g * 4) = pk;
}

// ---------------------------------------------------------------------------
// Kernel 2: MFMA flash attention.
// Block = 256 threads = 4 waves. Wave w: q-tile qt=w&1 (16 q), kv-half kvh=w>>1
// (2048 keys). S^T = K*Q^T (swapped operands -> lane-local softmax rows),
// P bounced via LDS to PV A-frags, 2-way flash merge at the end.
// All LDS tiles: 64 bf16/row (128B pitch), XOR-swizzled byte^=(row&7)<<4.
// ---------------------------------------------------------------------------
#define KOFF  0        // K tiles: 2 x [64][64] bf16 = 16384 B (reused as Obuf)
#define VOFF  16384    // Vt tiles: 2 x [128][64] bf16 = 32768 B
#define POFF  49152    // P: 4 waves x [16][64] bf16 = 8192 B

__global__ __launch_bounds__(256, 1)
void flash_attn_mfma(const float* __restrict__ userv,
                     const float* __restrict__ itemv,
                     const ushort* __restrict__ vprojT,
                     float* __restrict__ outp)
{
    const int side = blockIdx.x >> 7;   // 128 q-blocks per side
    const int qb   = blockIdx.x & 127;
    const float* __restrict__ X = side ? itemv : userv;
    const ushort* __restrict__ V = vprojT + (size_t)side * HID * N_NODES;
    float* __restrict__ O = outp + (size_t)side * N_NODES * HID;

    __shared__ __align__(16) char smem[57344];
    __shared__ float mB[32], lB[32];

    const int t = threadIdx.x;
    const int w = t >> 6, lane = t & 63;
    const int qt = w & 1, kvh = w >> 1;
    const int g = lane >> 4, qi = lane & 15;
    const int sw = (qi & 7) << 4;

    // Q fragments, 1/8 softmax scale folded in. B-frag: col=q(lane&15),
    // k(d) = 8*(lane>>4)+j per 32-wide chunk.
    bf16x8 qf[2];
    {
        const float* qp = X + (size_t)(qb * 32 + qt * 16 + qi) * DIM + g * 8;
        #pragma unroll
        for (int c = 0; c < 2; ++c) {
            float4 v0 = *(const float4*)(qp + c * 32);
            float4 v1 = *(const float4*)(qp + c * 32 + 4);
            union { unsigned u[4]; bf16x8 s; } r;
            r.u[0] = pk2(v0.x * 0.125f, v0.y * 0.125f);
            r.u[1] = pk2(v0.z * 0.125f, v0.w * 0.125f);
            r.u[2] = pk2(v1.x * 0.125f, v1.y * 0.125f);
            r.u[3] = pk2(v1.z * 0.125f, v1.w * 0.125f);
            qf[c] = r.s;
        }
    }

    f32x4 o[8];
    #pragma unroll
    for (int i = 0; i < 8; ++i) o[i] = f32x4{0.f, 0.f, 0.f, 0.f};
    float mrun = -INFINITY, lrun = 0.f;

    for (int it = 0; it < 32; ++it) {
        // ---- stage both kv-halves: K (f32->bf16) and Vt (bf16 copy) ----
        #pragma unroll
        for (int i = 0; i < 8; ++i) {
            int c = t + 256 * i;               // 2048 float4 chunks
            int tile = c >> 10, rem = c & 1023;
            int row = rem >> 4, seg = rem & 15;
            int k0 = (tile ? 2048 : 0) + it * 64;
            float4 v = *(const float4*)(X + (size_t)(k0 + row) * DIM + seg * 4);
            uint2 p; p.x = pk2(v.x, v.y); p.y = pk2(v.z, v.w);
            int off = KOFF + tile * 8192 + row * 128 + seg * 8;
            off ^= (row & 7) << 4;
            *(uint2*)(smem + off) = p;
        }
        #pragma unroll
        for (int i = 0; i < 8; ++i) {
            int c = t + 256 * i;               // 2048 16B chunks
            int tile = c >> 10, rem = c & 1023;
            int hh = rem >> 3, seg = rem & 7;
            int k0 = (tile ? 2048 : 0) + it * 64;
            uint4 v = *(const uint4*)(V + (size_t)hh * N_NODES + k0 + seg * 8);
            int off = VOFF + tile * 16384 + hh * 128 + seg * 16;
            off ^= (hh & 7) << 4;
            *(uint4*)(smem + off) = v;
        }
        __syncthreads();

        // ---- S^T = K * Q^T (4 key-tiles of 16) ----
        // A-frag: row=key(lane&15), k contiguous. D: col=q(lane&15), row=key.
        f32x4 s[4];
        #pragma unroll
        for (int i = 0; i < 4; ++i) {
            int base = KOFF + kvh * 8192 + (i * 16 + qi) * 128 + g * 16;
            bf16x8 a0 = *(const bf16x8*)(smem + ((base)      ^ sw));
            bf16x8 a1 = *(const bf16x8*)(smem + ((base + 64) ^ sw));
            f32x4 acc = f32x4{0.f, 0.f, 0.f, 0.f};
            acc = __builtin_amdgcn_mfma_f32_16x16x32_bf16(a0, qf[0], acc, 0, 0, 0);
            acc = __builtin_amdgcn_mfma_f32_16x16x32_bf16(a1, qf[1], acc, 0, 0, 0);
            s[i] = acc;
        }

        // ---- online softmax: lane owns q=qi, 16 key values ----
        float mx = -INFINITY;
        #pragma unroll
        for (int i = 0; i < 4; ++i) {
            mx = fmaxf(mx, fmaxf(fmaxf(s[i][0], s[i][1]), fmaxf(s[i][2], s[i][3])));
        }
        mx = fmaxf(mx, __shfl_xor(mx, 16));
        mx = fmaxf(mx, __shfl_xor(mx, 32));
        float mnew = fmaxf(mrun, mx);
        float rsc = __expf(mrun - mnew);       // 0 on first tile
        float ps = 0.f;
        unsigned pw[8];
        #pragma unroll
        for (int i = 0; i < 4; ++i) {
            float p0 = __expf(s[i][0] - mnew);
            float p1 = __expf(s[i][1] - mnew);
            float p2 = __expf(s[i][2] - mnew);
            float p3 = __expf(s[i][3] - mnew);
            ps += (p0 + p1) + (p2 + p3);
            pw[i * 2]     = pk2(p0, p1);
            pw[i * 2 + 1] = pk2(p2, p3);
        }
        ps += __shfl_xor(ps, 16);
        ps += __shfl_xor(ps, 32);
        lrun = lrun * rsc + ps;
        mrun = mnew;

        // ---- write P[q][key] bf16 (key = i*16 + 4g + reg) ----
        {
            int base = POFF + w * 2048 + qi * 128 + g * 8;
            #pragma unroll
            for (int i = 0; i < 4; ++i) {
                *(unsigned*)(smem + ((base + i * 32)     ^ sw)) = pw[i * 2];
                *(unsigned*)(smem + ((base + i * 32 + 4) ^ sw)) = pw[i * 2 + 1];
            }
        }

        // ---- rescale O by r (per q-row = 4g+reg) ----
        {
            f32x4 rv;
            #pragma unroll
            for (int r = 0; r < 4; ++r) rv[r] = __shfl(rsc, 4 * g + r);
            #pragma unroll
            for (int ht = 0; ht < 8; ++ht) o[ht] *= rv;
        }

        // ---- PV: O += P * V ----
        {
            int pbase = POFF + w * 2048 + qi * 128 + g * 16;
            bf16x8 pa0 = *(const bf16x8*)(smem + ((pbase)      ^ sw));
            bf16x8 pa1 = *(const bf16x8*)(smem + ((pbase + 64) ^ sw));
            #pragma unroll
            for (int ht = 0; ht < 8; ++ht) {
                int vbase = VOFF + kvh * 16384 + (ht * 16 + qi) * 128 + g * 16;
                bf16x8 b0 = *(const bf16x8*)(smem + ((vbase)      ^ sw));
                bf16x8 b1 = *(const bf16x8*)(smem + ((vbase + 64) ^ sw));
                o[ht] = __builtin_amdgcn_mfma_f32_16x16x32_bf16(pa0, b0, o[ht], 0, 0, 0);
                o[ht] = __builtin_amdgcn_mfma_f32_16x16x32_bf16(pa1, b1, o[ht], 0, 0, 0);
            }
        }
        __syncthreads();
    }

    // ---- 2-way flash merge (kvh=1 -> LDS over dead K region) ----
    if (kvh == 1) {
        #pragma unroll
        for (int ht = 0; ht < 8; ++ht) {
            int off = (KOFF + qt * 8192 + lane * 128 + ht * 16) ^ ((lane & 7) << 4);
            *(f32x4*)(smem + off) = o[ht];
        }
        if (lane < 16) { mB[qt * 16 + lane] = mrun; lB[qt * 16 + lane] = lrun; }
    }
    __syncthreads();
    if (kvh == 0) {
        float mb = mB[qt * 16 + qi], lb = lB[qt * 16 + qi];
        float ms = fmaxf(mrun, mb);
        float sa = __expf(mrun - ms), sb = __expf(mb - ms);
        float li = 1.0f / (lrun * sa + lb * sb);
        f32x4 sav, sbv, liv;
        #pragma unroll
        for (int r = 0; r < 4; ++r) {
            sav[r] = __shfl(sa, 4 * g + r);
            sbv[r] = __shfl(sb, 4 * g + r);
            liv[r] = __shfl(li, 4 * g + r);
        }
        const int q0 = qb * 32 + qt * 16;
        #pragma unroll
        for (int ht = 0; ht < 8; ++ht) {
            int off = (KOFF + qt * 8192 + lane * 128 + ht * 16) ^ ((lane & 7) << 4);
            f32x4 ob = *(const f32x4*)(smem + off);
            f32x4 r = (o[ht] * sav + ob * sbv) * liv;
            #pragma unroll
            for (int rr = 0; rr < 4; ++rr) {
                O[(size_t)(q0 + 4 * g + rr) * HID + ht * 16 + qi] = fmaxf(r[rr], 0.f);
            }
        }
    }
}

// ---------------------------------------------------------------------------
extern "C" void kernel_launch(void* const* d_in, const int* in_sizes, int n_in,
                              void* d_out, int out_size, void* d_ws, size_t ws_size,
                              hipStream_t stream)
{
    const float* review = (const float*)d_in[0];
    const float* userv  = (const float*)d_in[1];
    const float* itemv  = (const float*)d_in[2];
    const float* uW     = (const float*)d_in[3];
    const float* iW     = (const float*)d_in[4];
    const int*   adj0   = (const int*)d_in[5];
    const int*   adj1   = (const int*)d_in[6];
    const int*   adj2   = (const int*)d_in[7];
    const int*   adj3   = (const int*)d_in[8];
    float* out = (float*)d_out;
    ushort* vprojT = (ushort*)d_ws;   // 2 sides * 128 * 4096 * 2B = 2 MB

    gather_project<<<1024, 256, 0, stream>>>(review, userv, itemv, uW, iW,
                                             adj0, adj1, adj2, adj3, vprojT);
    flash_attn_mfma<<<256, 256, 0, stream>>>(userv, itemv, vprojT, out);
}

// Round 3
// 97.177 us; speedup vs baseline: 5.2580x; 3.2433x over previous
//
#include <hip/hip_runtime.h>
#include <hip/hip_bf16.h>
#include <math.h>

#define N_NODES 4096
#define N_REV 100000
#define DEG 16
#define DIM 64
#define HID 128
#define KCAT 2048   // DEG*2*DIM

typedef __attribute__((ext_vector_type(8))) short bf16x8;
typedef __attribute__((ext_vector_type(4))) float f32x4;

static __device__ __forceinline__ unsigned pk2(float a, float b) {
    __hip_bfloat162 h = __float22bfloat162_rn(make_float2(a, b));
    return *reinterpret_cast<unsigned*>(&h);
}

static __device__ __forceinline__ void gl_lds16(const void* g, void* l) {
    __builtin_amdgcn_global_load_lds(
        (const __attribute__((address_space(1))) unsigned int*)g,
        (__attribute__((address_space(3))) unsigned int*)l, 16, 0, 0);
}

// ---------------------------------------------------------------------------
// Prep 1: f32 -> bf16 (8 elems / thread)
// ---------------------------------------------------------------------------
__global__ __launch_bounds__(256)
void to_bf16_kernel(const float* __restrict__ src, ushort* __restrict__ dst, int n8)
{
    int i = blockIdx.x * 256 + threadIdx.x;
    if (i >= n8) return;
    float4 a = ((const float4*)src)[i * 2];
    float4 b = ((const float4*)src)[i * 2 + 1];
    uint4 o;
    o.x = pk2(a.x, a.y); o.y = pk2(a.z, a.w);
    o.z = pk2(b.x, b.y); o.w = pk2(b.z, b.w);
    ((uint4*)dst)[i] = o;
}

// ---------------------------------------------------------------------------
// Prep 2: W [2048][128] f32 -> wt tiles: chunk(side,kc,h,seg) 16B holds bf16 of
// W[kc*64 + (seg^(h&7))*8 + j][h]  (transposed + XOR-swizzle pre-applied)
// ---------------------------------------------------------------------------
__global__ __launch_bounds__(256)
void prep_w_kernel(const float* __restrict__ uW, const float* __restrict__ iW,
                   ushort* __restrict__ wt)
{
    const int side = blockIdx.x >> 5, kc = blockIdx.x & 31;
    const float* __restrict__ W = side ? iW : uW;
    __shared__ float wt_f[64 * 128];
    const int t = threadIdx.x;
    const float4* src = (const float4*)(W + (size_t)kc * 64 * 128);
    #pragma unroll
    for (int j = 0; j < 8; ++j)
        ((float4*)wt_f)[j * 256 + t] = src[j * 256 + t];
    __syncthreads();
    #pragma unroll
    for (int j = 0; j < 4; ++j) {
        int c = j * 256 + t;
        int h = c >> 3, seg = c & 7;
        int sp = seg ^ (h & 7);
        float v[8];
        #pragma unroll
        for (int jj = 0; jj < 8; ++jj) v[jj] = wt_f[(sp * 8 + jj) * 128 + h];
        uint4 o;
        o.x = pk2(v[0], v[1]); o.y = pk2(v[2], v[3]);
        o.z = pk2(v[4], v[5]); o.w = pk2(v[6], v[7]);
        *(uint4*)(wt + ((size_t)(side * 32 + kc) * 1024 + c) * 8) = o;
    }
}

// ---------------------------------------------------------------------------
// Kernel 1: MFMA gather-GEMM. vprojT[side][h][n] = bf16(sum_k cv[n][k]*W[k][h])
// Block: 32 nodes x 128 hid, 4 waves (2M x 2N). K-steps of 64 = one gathered
// 64-vec per row (d = kc>>1, half = kc&1). All staging via global_load_lds
// with swizzle folded into the per-lane global source address.
// ---------------------------------------------------------------------------
#define GA_OFF 0        // A tile: 32 rows x 64 bf16 = 4 KB
#define GW_OFF 4096     // W tile: 128 rows x 64 bf16 = 16 KB
#define GADJ_OFF 20480  // adj: 2 x 32 x 16 ints = 4 KB

__global__ __launch_bounds__(256)
void gemm_gather(const ushort* __restrict__ Rb, const ushort* __restrict__ Ub,
                 const ushort* __restrict__ Ib, const ushort* __restrict__ wt,
                 const int* __restrict__ adj0, const int* __restrict__ adj1,
                 const int* __restrict__ adj2, const int* __restrict__ adj3,
                 ushort* __restrict__ vprojT)
{
    const int side = blockIdx.x >> 7, tile = blockIdx.x & 127;
    const int* __restrict__ adjA = side ? adj2 : adj0;
    const int* __restrict__ adjB = side ? adj3 : adj1;
    const ushort* __restrict__ vecB = side ? Ub : Ib;
    ushort* __restrict__ outT = vprojT + (size_t)side * HID * N_NODES;

    __shared__ __align__(16) char smem[24576];
    int* adjs = (int*)(smem + GADJ_OFF);
    const int t = threadIdx.x;
    const int w = t >> 6, lane = t & 63;
    const int wm = w >> 1, wn = w & 1;
    const int g = lane >> 4, qi = lane & 15;
    const int swz = (qi & 7) << 4;

    // stage adjacency rows for this tile (512 + 512 ints, contiguous)
    if (t < 128)
        ((int4*)adjs)[t] = ((const int4*)(adjA + tile * 512))[t];
    else
        ((int4*)adjs)[t + 0] = ((const int4*)(adjB + tile * 512))[t - 128];
    __syncthreads();

    f32x4 acc[4];
    #pragma unroll
    for (int i = 0; i < 4; ++i) acc[i] = f32x4{0.f, 0.f, 0.f, 0.f};

    const int r = t >> 3, s = t & 7;
    const int sp8 = (s ^ (r & 7)) * 8;

    for (int kc = 0; kc < 32; ++kc) {
        const int d = kc >> 1, half = kc & 1;
        if (kc) __syncthreads();
        // A tile: gathered 64-vecs, one 16B chunk per thread
        {
            const ushort* vsrc = half ? vecB : Rb;
            int idx = adjs[half * 512 + r * 16 + d];
            gl_lds16(vsrc + (size_t)idx * 64 + sp8,
                     smem + GA_OFF + (t >> 6) * 1024);
        }
        // W tile: linear pre-swizzled copy, 4 chunks per thread
        {
            const ushort* wsrc = wt + (size_t)(side * 32 + kc) * 1024 * 8;
            #pragma unroll
            for (int j = 0; j < 4; ++j)
                gl_lds16(wsrc + (size_t)(j * 256 + t) * 8,
                         smem + GW_OFF + j * 4096 + (t >> 6) * 1024);
        }
        __syncthreads();

        const int abase = (wm * 16 + qi) * 128 + g * 16;
        bf16x8 a0 = *(const bf16x8*)(smem + ((abase)      ^ swz));
        bf16x8 a1 = *(const bf16x8*)(smem + ((abase + 64) ^ swz));
        #pragma unroll
        for (int nf = 0; nf < 4; ++nf) {
            int bbase = GW_OFF + (wn * 64 + nf * 16 + qi) * 128 + g * 16;
            bf16x8 b0 = *(const bf16x8*)(smem + ((bbase)      ^ swz));
            bf16x8 b1 = *(const bf16x8*)(smem + ((bbase + 64) ^ swz));
            acc[nf] = __builtin_amdgcn_mfma_f32_16x16x32_bf16(a0, b0, acc[nf], 0, 0, 0);
            acc[nf] = __builtin_amdgcn_mfma_f32_16x16x32_bf16(a1, b1, acc[nf], 0, 0, 0);
        }
    }

    // epilogue: transposed bf16 store (4 consecutive n per 8B)
    #pragma unroll
    for (int nf = 0; nf < 4; ++nf) {
        int h = wn * 64 + nf * 16 + qi;
        uint2 p;
        p.x = pk2(acc[nf][0], acc[nf][1]);
        p.y = pk2(acc[nf][2], acc[nf][3]);
        *(uint2*)(outT + (size_t)h * N_NODES + tile * 32 + wm * 16 + g * 4) = p;
    }
}

// ---------------------------------------------------------------------------
// Kernel 2: MFMA flash attention (as R2), staging via global_load_lds from
// pre-converted bf16 X and vprojT (swizzle folded into per-lane source addr).
// ---------------------------------------------------------------------------
#define KOFF  0        // K tiles: 2 x [64][64] bf16 = 16384 B (reused as Obuf)
#define VOFF  16384    // Vt tiles: 2 x [128][64] bf16 = 32768 B
#define POFF  49152    // P: 4 waves x [16][64] bf16 = 8192 B

__global__ __launch_bounds__(256, 1)
void flash_attn_mfma(const float* __restrict__ userv,
                     const float* __restrict__ itemv,
                     const ushort* __restrict__ Ub,
                     const ushort* __restrict__ Ib,
                     const ushort* __restrict__ vprojT,
                     float* __restrict__ outp)
{
    const int side = blockIdx.x >> 7;   // 128 q-blocks per side
    const int qb   = blockIdx.x & 127;
    const float* __restrict__ X = side ? itemv : userv;
    const ushort* __restrict__ Xb = side ? Ib : Ub;
    const ushort* __restrict__ V = vprojT + (size_t)side * HID * N_NODES;
    float* __restrict__ O = outp + (size_t)side * N_NODES * HID;

    __shared__ __align__(16) char smem[57344];
    __shared__ float mB[32], lB[32];

    const int t = threadIdx.x;
    const int w = t >> 6, lane = t & 63;
    const int qt = w & 1, kvh = w >> 1;
    const int g = lane >> 4, qi = lane & 15;
    const int sw = (qi & 7) << 4;

    // Q fragments, 1/8 softmax scale folded in (from f32 source).
    bf16x8 qf[2];
    {
        const float* qp = X + (size_t)(qb * 32 + qt * 16 + qi) * DIM + g * 8;
        #pragma unroll
        for (int c = 0; c < 2; ++c) {
            float4 v0 = *(const float4*)(qp + c * 32);
            float4 v1 = *(const float4*)(qp + c * 32 + 4);
            union { unsigned u[4]; bf16x8 s; } rr;
            rr.u[0] = pk2(v0.x * 0.125f, v0.y * 0.125f);
            rr.u[1] = pk2(v0.z * 0.125f, v0.w * 0.125f);
            rr.u[2] = pk2(v1.x * 0.125f, v1.y * 0.125f);
            rr.u[3] = pk2(v1.z * 0.125f, v1.w * 0.125f);
            qf[c] = rr.s;
        }
    }

    f32x4 o[8];
    #pragma unroll
    for (int i = 0; i < 8; ++i) o[i] = f32x4{0.f, 0.f, 0.f, 0.f};
    float mrun = -INFINITY, lrun = 0.f;

    for (int it = 0; it < 32; ++it) {
        const int k0 = it * 64;
        __syncthreads();   // prev tile fully consumed

        // K tiles (both kv-halves): 1024 chunks of 16B
        #pragma unroll
        for (int j = 0; j < 4; ++j) {
            int c = j * 256 + t;
            int tile = c >> 9, rem = c & 511;
            int row = rem >> 3, seg = rem & 7;
            const ushort* src = Xb + (size_t)(tile * 2048 + k0 + row) * 64
                                   + (seg ^ (row & 7)) * 8;
            gl_lds16(src, smem + KOFF + (c >> 6) * 1024);
        }
        // V tiles: 2048 chunks of 16B
        #pragma unroll
        for (int j = 0; j < 8; ++j) {
            int c = j * 256 + t;
            int tile = c >> 10, rem = c & 1023;
            int hh = rem >> 3, seg = rem & 7;
            const ushort* src = V + (size_t)hh * N_NODES + tile * 2048 + k0
                                  + (seg ^ (hh & 7)) * 8;
            gl_lds16(src, smem + VOFF + (c >> 6) * 1024);
        }
        __syncthreads();

        // ---- S^T = K * Q^T ----
        f32x4 s[4];
        #pragma unroll
        for (int i = 0; i < 4; ++i) {
            int base = KOFF + kvh * 8192 + (i * 16 + qi) * 128 + g * 16;
            bf16x8 a0 = *(const bf16x8*)(smem + ((base)      ^ sw));
            bf16x8 a1 = *(const bf16x8*)(smem + ((base + 64) ^ sw));
            f32x4 acc = f32x4{0.f, 0.f, 0.f, 0.f};
            acc = __builtin_amdgcn_mfma_f32_16x16x32_bf16(a0, qf[0], acc, 0, 0, 0);
            acc = __builtin_amdgcn_mfma_f32_16x16x32_bf16(a1, qf[1], acc, 0, 0, 0);
            s[i] = acc;
        }

        // ---- online softmax (lane owns q=qi across 16 keys) ----
        float mx = -INFINITY;
        #pragma unroll
        for (int i = 0; i < 4; ++i)
            mx = fmaxf(mx, fmaxf(fmaxf(s[i][0], s[i][1]), fmaxf(s[i][2], s[i][3])));
        mx = fmaxf(mx, __shfl_xor(mx, 16));
        mx = fmaxf(mx, __shfl_xor(mx, 32));
        float mnew = fmaxf(mrun, mx);
        float rsc = __expf(mrun - mnew);
        float ps = 0.f;
        unsigned pw[8];
        #pragma unroll
        for (int i = 0; i < 4; ++i) {
            float p0 = __expf(s[i][0] - mnew);
            float p1 = __expf(s[i][1] - mnew);
            float p2 = __expf(s[i][2] - mnew);
            float p3 = __expf(s[i][3] - mnew);
            ps += (p0 + p1) + (p2 + p3);
            pw[i * 2]     = pk2(p0, p1);
            pw[i * 2 + 1] = pk2(p2, p3);
        }
        ps += __shfl_xor(ps, 16);
        ps += __shfl_xor(ps, 32);
        lrun = lrun * rsc + ps;
        mrun = mnew;

        // ---- write P[q][key] bf16 ----
        {
            int base = POFF + w * 2048 + qi * 128 + g * 8;
            #pragma unroll
            for (int i = 0; i < 4; ++i) {
                *(unsigned*)(smem + ((base + i * 32)     ^ sw)) = pw[i * 2];
                *(unsigned*)(smem + ((base + i * 32 + 4) ^ sw)) = pw[i * 2 + 1];
            }
        }

        // ---- rescale O ----
        {
            f32x4 rv;
            #pragma unroll
            for (int rr = 0; rr < 4; ++rr) rv[rr] = __shfl(rsc, 4 * g + rr);
            #pragma unroll
            for (int ht = 0; ht < 8; ++ht) o[ht] *= rv;
        }

        // ---- PV ----
        {
            int pbase = POFF + w * 2048 + qi * 128 + g * 16;
            bf16x8 pa0 = *(const bf16x8*)(smem + ((pbase)      ^ sw));
            bf16x8 pa1 = *(const bf16x8*)(smem + ((pbase + 64) ^ sw));
            #pragma unroll
            for (int ht = 0; ht < 8; ++ht) {
                int vbase = VOFF + kvh * 16384 + (ht * 16 + qi) * 128 + g * 16;
                bf16x8 b0 = *(const bf16x8*)(smem + ((vbase)      ^ sw));
                bf16x8 b1 = *(const bf16x8*)(smem + ((vbase + 64) ^ sw));
                o[ht] = __builtin_amdgcn_mfma_f32_16x16x32_bf16(pa0, b0, o[ht], 0, 0, 0);
                o[ht] = __builtin_amdgcn_mfma_f32_16x16x32_bf16(pa1, b1, o[ht], 0, 0, 0);
            }
        }
        __syncthreads();
    }

    // ---- 2-way flash merge ----
    if (kvh == 1) {
        #pragma unroll
        for (int ht = 0; ht < 8; ++ht) {
            int off = (KOFF + qt * 8192 + lane * 128 + ht * 16) ^ ((lane & 7) << 4);
            *(f32x4*)(smem + off) = o[ht];
        }
        if (lane < 16) { mB[qt * 16 + lane] = mrun; lB[qt * 16 + lane] = lrun; }
    }
    __syncthreads();
    if (kvh == 0) {
        float mb = mB[qt * 16 + qi], lb = lB[qt * 16 + qi];
        float ms = fmaxf(mrun, mb);
        float sa = __expf(mrun - ms), sb = __expf(mb - ms);
        float li = 1.0f / (lrun * sa + lb * sb);
        f32x4 sav, sbv, liv;
        #pragma unroll
        for (int rr = 0; rr < 4; ++rr) {
            sav[rr] = __shfl(sa, 4 * g + rr);
            sbv[rr] = __shfl(sb, 4 * g + rr);
            liv[rr] = __shfl(li, 4 * g + rr);
        }
        const int q0 = qb * 32 + qt * 16;
        #pragma unroll
        for (int ht = 0; ht < 8; ++ht) {
            int off = (KOFF + qt * 8192 + lane * 128 + ht * 16) ^ ((lane & 7) << 4);
            f32x4 ob = *(const f32x4*)(smem + off);
            f32x4 rr = (o[ht] * sav + ob * sbv) * liv;
            #pragma unroll
            for (int r2 = 0; r2 < 4; ++r2)
                O[(size_t)(q0 + 4 * g + r2) * HID + ht * 16 + qi] = fmaxf(rr[r2], 0.f);
        }
    }
}

// ---------------------------------------------------------------------------
extern "C" void kernel_launch(void* const* d_in, const int* in_sizes, int n_in,
                              void* d_out, int out_size, void* d_ws, size_t ws_size,
                              hipStream_t stream)
{
    const float* review = (const float*)d_in[0];
    const float* userv  = (const float*)d_in[1];
    const float* itemv  = (const float*)d_in[2];
    const float* uW     = (const float*)d_in[3];
    const float* iW     = (const float*)d_in[4];
    const int*   adj0   = (const int*)d_in[5];
    const int*   adj1   = (const int*)d_in[6];
    const int*   adj2   = (const int*)d_in[7];
    const int*   adj3   = (const int*)d_in[8];
    float* out = (float*)d_out;

    // workspace layout (bytes)
    char* ws = (char*)d_ws;
    ushort* vprojT = (ushort*)(ws);                       // 2*128*4096*2   = 2 MB
    ushort* wt     = (ushort*)(ws + 2097152);             // 2*32*1024*16   = 1 MB
    ushort* Rb     = (ushort*)(ws + 3145728);             // 100000*64*2    = 12.8 MB
    ushort* Ub     = (ushort*)(ws + 15945728);            // 4096*64*2
    ushort* Ib     = (ushort*)(ws + 16470016);            // 4096*64*2  (end ~16.99 MB)

    to_bf16_kernel<<<3125, 256, 0, stream>>>(review, Rb, N_REV * DIM / 8);
    to_bf16_kernel<<<128, 256, 0, stream>>>(userv, Ub, N_NODES * DIM / 8);
    to_bf16_kernel<<<128, 256, 0, stream>>>(itemv, Ib, N_NODES * DIM / 8);
    prep_w_kernel<<<64, 256, 0, stream>>>(uW, iW, wt);

    gemm_gather<<<256, 256, 0, stream>>>(Rb, Ub, Ib, wt,
                                         adj0, adj1, adj2, adj3, vprojT);
    flash_attn_mfma<<<256, 256, 0, stream>>>(userv, itemv, Ub, Ib, vprojT, out);
}

// Round 4
// 81.254 us; speedup vs baseline: 6.2884x; 1.1960x over previous
//
#include <hip/hip_runtime.h>
#include <hip/hip_bf16.h>
#include <math.h>

#define N_NODES 4096
#define N_REV 100000
#define DEG 16
#define DIM 64
#define HID 128

typedef __attribute__((ext_vector_type(8))) short bf16x8;
typedef __attribute__((ext_vector_type(4))) float f32x4;

static __device__ __forceinline__ unsigned pk2(float a, float b) {
    __hip_bfloat162 h = __float22bfloat162_rn(make_float2(a, b));
    return *reinterpret_cast<unsigned*>(&h);
}

static __device__ __forceinline__ void gl_lds16(const void* g, void* l) {
    __builtin_amdgcn_global_load_lds(
        (const __attribute__((address_space(1))) unsigned int*)g,
        (__attribute__((address_space(3))) unsigned int*)l, 16, 0, 0);
}

// ---------------------------------------------------------------------------
// Prep 1: all three f32 vec arrays -> bf16 in one launch.
// ranges (in 16B chunks of 8 elems): R [0,800000) U [800000,832768) I [..865536)
// ---------------------------------------------------------------------------
__global__ __launch_bounds__(256)
void prep_vecs(const float* __restrict__ R, const float* __restrict__ U,
               const float* __restrict__ I, ushort* __restrict__ Rb,
               ushort* __restrict__ Ub, ushort* __restrict__ Ib)
{
    int i = blockIdx.x * 256 + threadIdx.x;
    const float* src; ushort* dst; int j;
    if (i < 800000)      { src = R; dst = Rb; j = i; }
    else if (i < 832768) { src = U; dst = Ub; j = i - 800000; }
    else if (i < 865536) { src = I; dst = Ib; j = i - 832768; }
    else return;
    float4 a = ((const float4*)src)[j * 2];
    float4 b = ((const float4*)src)[j * 2 + 1];
    uint4 o;
    o.x = pk2(a.x, a.y); o.y = pk2(a.z, a.w);
    o.z = pk2(b.x, b.y); o.w = pk2(b.z, b.w);
    ((uint4*)dst)[j] = o;
}

// ---------------------------------------------------------------------------
// Prep 2: W [2048][128] f32 -> wt tiles, transposed + XOR-swizzle pre-applied.
// ---------------------------------------------------------------------------
__global__ __launch_bounds__(256)
void prep_w_kernel(const float* __restrict__ uW, const float* __restrict__ iW,
                   ushort* __restrict__ wt)
{
    const int side = blockIdx.x >> 5, kc = blockIdx.x & 31;
    const float* __restrict__ W = side ? iW : uW;
    __shared__ float wt_f[64 * 128];
    const int t = threadIdx.x;
    const float4* src = (const float4*)(W + (size_t)kc * 64 * 128);
    #pragma unroll
    for (int j = 0; j < 8; ++j)
        ((float4*)wt_f)[j * 256 + t] = src[j * 256 + t];
    __syncthreads();
    #pragma unroll
    for (int j = 0; j < 4; ++j) {
        int c = j * 256 + t;
        int h = c >> 3, seg = c & 7;
        int sp = seg ^ (h & 7);
        float v[8];
        #pragma unroll
        for (int jj = 0; jj < 8; ++jj) v[jj] = wt_f[(sp * 8 + jj) * 128 + h];
        uint4 o;
        o.x = pk2(v[0], v[1]); o.y = pk2(v[2], v[3]);
        o.z = pk2(v[4], v[5]); o.w = pk2(v[6], v[7]);
        *(uint4*)(wt + ((size_t)(side * 32 + kc) * 1024 + c) * 8) = o;
    }
}

// ---------------------------------------------------------------------------
// Kernel 1: MFMA gather-GEMM with 2-phase prefetch.
// Block: 32 nodes x 128 hid, 4 waves (2M x 2N). K-steps of 64.
// LDS: 2 bufs x (A 4KB + W 16KB) + adj 4KB = 44KB.
// ---------------------------------------------------------------------------
#define GB_STRIDE 20480
#define GADJ_OFF  40960

__global__ __launch_bounds__(256)
void gemm_gather(const ushort* __restrict__ Rb, const ushort* __restrict__ Ub,
                 const ushort* __restrict__ Ib, const ushort* __restrict__ wt,
                 const int* __restrict__ adj0, const int* __restrict__ adj1,
                 const int* __restrict__ adj2, const int* __restrict__ adj3,
                 ushort* __restrict__ vprojT)
{
    const int side = blockIdx.x >> 7, tile = blockIdx.x & 127;
    const int* __restrict__ adjA = side ? adj2 : adj0;
    const int* __restrict__ adjB = side ? adj3 : adj1;
    const ushort* __restrict__ vecB = side ? Ub : Ib;
    const ushort* __restrict__ wbase = wt + (size_t)side * 32 * 8192;
    ushort* __restrict__ outT = vprojT + (size_t)side * HID * N_NODES;

    __shared__ __align__(16) char smem[45056];
    int* adjs = (int*)(smem + GADJ_OFF);
    const int t = threadIdx.x;
    const int w = t >> 6, lane = t & 63;
    const int wm = w >> 1, wn = w & 1;
    const int g = lane >> 4, qi = lane & 15;
    const int swz = (qi & 7) << 4;
    const int r = t >> 3, s = t & 7;
    const int sp8 = (s ^ (r & 7)) * 8;

    if (t < 128)
        ((int4*)adjs)[t] = ((const int4*)(adjA + tile * 512))[t];
    else
        ((int4*)adjs)[t] = ((const int4*)(adjB + tile * 512))[t - 128];
    __syncthreads();

    f32x4 acc[4];
    #pragma unroll
    for (int i = 0; i < 4; ++i) acc[i] = f32x4{0.f, 0.f, 0.f, 0.f};

    // ---- stage one kc step into buffer b ----
    auto stage = [&](int kc, int b) {
        const int d = kc >> 1, half = kc & 1;
        char* base = smem + b * GB_STRIDE;
        const ushort* vsrc = half ? vecB : Rb;
        int idx = adjs[half * 512 + r * 16 + d];
        gl_lds16(vsrc + (size_t)idx * 64 + sp8, base + (t >> 6) * 1024);
        const ushort* wsrc = wbase + (size_t)kc * 8192;
        #pragma unroll
        for (int j = 0; j < 4; ++j)
            gl_lds16(wsrc + (size_t)(j * 256 + t) * 8,
                     base + 4096 + j * 4096 + (t >> 6) * 1024);
    };

    stage(0, 0);
    __syncthreads();

    for (int kc = 0; kc < 32; ++kc) {
        const int cur = kc & 1;
        if (kc < 31) stage(kc + 1, cur ^ 1);

        const char* cb = smem + cur * GB_STRIDE;
        const int abase = (wm * 16 + qi) * 128 + g * 16;
        bf16x8 a0 = *(const bf16x8*)(cb + ((abase)      ^ swz));
        bf16x8 a1 = *(const bf16x8*)(cb + ((abase + 64) ^ swz));
        #pragma unroll
        for (int nf = 0; nf < 4; ++nf) {
            int bbase = 4096 + (wn * 64 + nf * 16 + qi) * 128 + g * 16;
            bf16x8 b0 = *(const bf16x8*)(cb + ((bbase)      ^ swz));
            bf16x8 b1 = *(const bf16x8*)(cb + ((bbase + 64) ^ swz));
            acc[nf] = __builtin_amdgcn_mfma_f32_16x16x32_bf16(a0, b0, acc[nf], 0, 0, 0);
            acc[nf] = __builtin_amdgcn_mfma_f32_16x16x32_bf16(a1, b1, acc[nf], 0, 0, 0);
        }
        __syncthreads();
    }

    #pragma unroll
    for (int nf = 0; nf < 4; ++nf) {
        int h = wn * 64 + nf * 16 + qi;
        uint2 p;
        p.x = pk2(acc[nf][0], acc[nf][1]);
        p.y = pk2(acc[nf][2], acc[nf][3]);
        *(uint2*)(outT + (size_t)h * N_NODES + tile * 32 + wm * 16 + g * 4) = p;
    }
}

// ---------------------------------------------------------------------------
// Kernel 2: MFMA flash attention, kv-split across 2 blocks + 2-phase prefetch.
// Block: (side, qb, kvb): 32 q x 2048 keys. 4 waves = (qt, kvq); each wave
// 16 q x 1024 keys. 32 iters of 64 keys (32 per kvq). Emits unnormalized
// partials (o, m, l) to workspace; merge_halves finishes.
// LDS: 2 bufs x (K [64][64] 8KB + V [128][64] 16KB) + P 8KB = 56KB.
// ---------------------------------------------------------------------------
#define FB_STRIDE 24576
#define FV_OFF    8192
#define FP_OFF    49152

__global__ __launch_bounds__(256, 2)
void flash_attn_mfma(const float* __restrict__ userv,
                     const float* __restrict__ itemv,
                     const ushort* __restrict__ Ub,
                     const ushort* __restrict__ Ib,
                     const ushort* __restrict__ vprojT,
                     float* __restrict__ po,
                     float* __restrict__ pm,
                     float* __restrict__ pl)
{
    const int side = blockIdx.x >> 8;
    const int rem  = blockIdx.x & 255;
    const int qb   = rem >> 1;
    const int kvb  = rem & 1;
    const float* __restrict__ X = side ? itemv : userv;
    const ushort* __restrict__ Xb = side ? Ib : Ub;
    const ushort* __restrict__ V = vprojT + (size_t)side * HID * N_NODES;
    const int part = side * 2 + kvb;

    __shared__ __align__(16) char smem[57344];
    __shared__ float mB[32], lB[32];

    const int t = threadIdx.x;
    const int w = t >> 6, lane = t & 63;
    const int qt = w & 1, kvq = w >> 1;
    const int g = lane >> 4, qi = lane & 15;
    const int sw = (qi & 7) << 4;

    // Q fragments with 1/8 scale folded in (f32 source).
    bf16x8 qf[2];
    {
        const float* qp = X + (size_t)(qb * 32 + qt * 16 + qi) * DIM + g * 8;
        #pragma unroll
        for (int c = 0; c < 2; ++c) {
            float4 v0 = *(const float4*)(qp + c * 32);
            float4 v1 = *(const float4*)(qp + c * 32 + 4);
            union { unsigned u[4]; bf16x8 s; } rr;
            rr.u[0] = pk2(v0.x * 0.125f, v0.y * 0.125f);
            rr.u[1] = pk2(v0.z * 0.125f, v0.w * 0.125f);
            rr.u[2] = pk2(v1.x * 0.125f, v1.y * 0.125f);
            rr.u[3] = pk2(v1.z * 0.125f, v1.w * 0.125f);
            qf[c] = rr.s;
        }
    }

    f32x4 o[8];
    #pragma unroll
    for (int i = 0; i < 8; ++i) o[i] = f32x4{0.f, 0.f, 0.f, 0.f};
    float mrun = -INFINITY, lrun = 0.f;

    // ---- stage 64 keys (K + V) for iter `it` into buffer b ----
    auto stage = [&](int it, int b) {
        const int kbase = kvb * 2048 + it * 64;
        char* base = smem + b * FB_STRIDE;
        #pragma unroll
        for (int j = 0; j < 2; ++j) {
            int c = j * 256 + t;
            int row = c >> 3, seg = c & 7;
            gl_lds16(Xb + (size_t)(kbase + row) * 64 + (seg ^ (row & 7)) * 8,
                     base + (c >> 6) * 1024);
        }
        #pragma unroll
        for (int j = 0; j < 4; ++j) {
            int c = j * 256 + t;
            int hh = c >> 3, seg = c & 7;
            gl_lds16(V + (size_t)hh * N_NODES + kbase + (seg ^ (hh & 7)) * 8,
                     base + FV_OFF + (c >> 6) * 1024);
        }
    };

    stage(0, 0);
    __syncthreads();

    for (int it = 0; it < 32; ++it) {
        const int cur = it & 1;
        if (it < 31) stage(it + 1, cur ^ 1);
        const char* cb = smem + cur * FB_STRIDE;

        // ---- S^T = K * Q^T : this wave's 32 keys (2 tiles of 16) ----
        f32x4 s[2];
        #pragma unroll
        for (int i = 0; i < 2; ++i) {
            int arow = kvq * 32 + i * 16 + qi;
            int abase = arow * 128 + g * 16;
            bf16x8 a0 = *(const bf16x8*)(cb + ((abase)      ^ sw));
            bf16x8 a1 = *(const bf16x8*)(cb + ((abase + 64) ^ sw));
            f32x4 acc = f32x4{0.f, 0.f, 0.f, 0.f};
            acc = __builtin_amdgcn_mfma_f32_16x16x32_bf16(a0, qf[0], acc, 0, 0, 0);
            acc = __builtin_amdgcn_mfma_f32_16x16x32_bf16(a1, qf[1], acc, 0, 0, 0);
            s[i] = acc;
        }

        // ---- online softmax (lane owns q=qi, 8 key values) ----
        float mx = fmaxf(fmaxf(fmaxf(s[0][0], s[0][1]), fmaxf(s[0][2], s[0][3])),
                         fmaxf(fmaxf(s[1][0], s[1][1]), fmaxf(s[1][2], s[1][3])));
        mx = fmaxf(mx, __shfl_xor(mx, 16));
        mx = fmaxf(mx, __shfl_xor(mx, 32));
        float mnew = fmaxf(mrun, mx);
        float rsc = __expf(mrun - mnew);
        float ps = 0.f;
        unsigned pw[4];
        #pragma unroll
        for (int i = 0; i < 2; ++i) {
            float p0 = __expf(s[i][0] - mnew);
            float p1 = __expf(s[i][1] - mnew);
            float p2 = __expf(s[i][2] - mnew);
            float p3 = __expf(s[i][3] - mnew);
            ps += (p0 + p1) + (p2 + p3);
            pw[i * 2]     = pk2(p0, p1);
            pw[i * 2 + 1] = pk2(p2, p3);
        }
        ps += __shfl_xor(ps, 16);
        ps += __shfl_xor(ps, 32);
        lrun = lrun * rsc + ps;
        mrun = mnew;

        // ---- write P[q][key] bf16 (per-wave region) ----
        {
            int base = FP_OFF + w * 2048 + qi * 128 + g * 8;
            #pragma unroll
            for (int i = 0; i < 2; ++i) {
                *(unsigned*)(smem + ((base + i * 32)     ^ sw)) = pw[i * 2];
                *(unsigned*)(smem + ((base + i * 32 + 4) ^ sw)) = pw[i * 2 + 1];
            }
        }

        // ---- rescale O ----
        {
            f32x4 rv;
            #pragma unroll
            for (int rr = 0; rr < 4; ++rr) rv[rr] = __shfl(rsc, 4 * g + rr);
            #pragma unroll
            for (int ht = 0; ht < 8; ++ht) o[ht] *= rv;
        }

        // ---- PV: O += P * V (K=32 per mfma) ----
        {
            int pbase = FP_OFF + w * 2048 + qi * 128 + g * 16;
            bf16x8 pa = *(const bf16x8*)(smem + (pbase ^ sw));
            #pragma unroll
            for (int ht = 0; ht < 8; ++ht) {
                int vbase = FV_OFF + (ht * 16 + qi) * 128 + kvq * 64 + g * 16;
                bf16x8 b0 = *(const bf16x8*)(cb + (vbase ^ sw));
                o[ht] = __builtin_amdgcn_mfma_f32_16x16x32_bf16(pa, b0, o[ht], 0, 0, 0);
            }
        }
        __syncthreads();
    }

    // ---- in-block 2-way merge over kvq, write partials ----
    if (kvq == 1) {
        #pragma unroll
        for (int ht = 0; ht < 8; ++ht) {
            int off = (qt * 8192 + lane * 128 + ht * 16) ^ ((lane & 7) << 4);
            *(f32x4*)(smem + off) = o[ht];
        }
        if (lane < 16) { mB[qt * 16 + lane] = mrun; lB[qt * 16 + lane] = lrun; }
    }
    __syncthreads();
    if (kvq == 0) {
        float mb = mB[qt * 16 + qi], lb = lB[qt * 16 + qi];
        float ms = fmaxf(mrun, mb);
        float sa = __expf(mrun - ms), sb = __expf(mb - ms);
        float lnew = lrun * sa + lb * sb;
        f32x4 sav, sbv;
        #pragma unroll
        for (int rr = 0; rr < 4; ++rr) {
            sav[rr] = __shfl(sa, 4 * g + rr);
            sbv[rr] = __shfl(sb, 4 * g + rr);
        }
        const int q0 = qb * 32 + qt * 16;
        float* pob = po + ((size_t)part * N_NODES + q0) * HID;
        #pragma unroll
        for (int ht = 0; ht < 8; ++ht) {
            int off = (qt * 8192 + lane * 128 + ht * 16) ^ ((lane & 7) << 4);
            f32x4 ob = *(const f32x4*)(smem + off);
            f32x4 rr = o[ht] * sav + ob * sbv;
            #pragma unroll
            for (int r2 = 0; r2 < 4; ++r2)
                pob[(size_t)(4 * g + r2) * HID + ht * 16 + qi] = rr[r2];
        }
        if (g == 0) {
            pm[part * N_NODES + q0 + qi] = ms;
            pl[part * N_NODES + q0 + qi] = lnew;
        }
    }
}

// ---------------------------------------------------------------------------
// Kernel 3: merge the two kv-half partials, normalize, relu.
// ---------------------------------------------------------------------------
__global__ __launch_bounds__(256)
void merge_halves(const float* __restrict__ po, const float* __restrict__ pm,
                  const float* __restrict__ pl, float* __restrict__ out)
{
    int idx = blockIdx.x * 256 + threadIdx.x;   // 2*4096*32
    int h4 = idx & 31;
    int q  = (idx >> 5) & 4095;
    int side = idx >> 17;
    float ma = pm[(side * 2 + 0) * N_NODES + q];
    float mb = pm[(side * 2 + 1) * N_NODES + q];
    float la = pl[(side * 2 + 0) * N_NODES + q];
    float lb = pl[(side * 2 + 1) * N_NODES + q];
    float M  = fmaxf(ma, mb);
    float sa = __expf(ma - M), sb = __expf(mb - M);
    float li = 1.0f / (la * sa + lb * sb);
    f32x4 a = *(const f32x4*)(po + (((size_t)(side * 2 + 0) * N_NODES + q) * HID) + h4 * 4);
    f32x4 b = *(const f32x4*)(po + (((size_t)(side * 2 + 1) * N_NODES + q) * HID) + h4 * 4);
    f32x4 r = (a * sa + b * sb) * li;
    f32x4 res;
    #pragma unroll
    for (int i = 0; i < 4; ++i) res[i] = fmaxf(r[i], 0.f);
    *(f32x4*)(out + ((size_t)side * N_NODES + q) * HID + h4 * 4) = res;
}

// ---------------------------------------------------------------------------
extern "C" void kernel_launch(void* const* d_in, const int* in_sizes, int n_in,
                              void* d_out, int out_size, void* d_ws, size_t ws_size,
                              hipStream_t stream)
{
    const float* review = (const float*)d_in[0];
    const float* userv  = (const float*)d_in[1];
    const float* itemv  = (const float*)d_in[2];
    const float* uW     = (const float*)d_in[3];
    const float* iW     = (const float*)d_in[4];
    const int*   adj0   = (const int*)d_in[5];
    const int*   adj1   = (const int*)d_in[6];
    const int*   adj2   = (const int*)d_in[7];
    const int*   adj3   = (const int*)d_in[8];
    float* out = (float*)d_out;

    // workspace layout (bytes); po aliases Rb (dead after gemm_gather).
    char* ws = (char*)d_ws;
    ushort* vprojT = (ushort*)(ws);               // 2 MB
    ushort* wt     = (ushort*)(ws + 2097152);     // 1 MB
    ushort* Rb     = (ushort*)(ws + 3145728);     // 12.8 MB (gemm only)
    float*  po     = (float*)(ws + 3145728);      // 8 MB, aliases Rb
    ushort* Ub     = (ushort*)(ws + 15945728);    // 512 KB
    ushort* Ib     = (ushort*)(ws + 16470016);    // 512 KB
    float*  pm     = (float*)(ws + 16994304);     // 64 KB
    float*  pl     = (float*)(ws + 17059840);     // 64 KB (end ~16.3 MB)

    prep_vecs<<<3381, 256, 0, stream>>>(review, userv, itemv, Rb, Ub, Ib);
    prep_w_kernel<<<64, 256, 0, stream>>>(uW, iW, wt);
    gemm_gather<<<256, 256, 0, stream>>>(Rb, Ub, Ib, wt,
                                         adj0, adj1, adj2, adj3, vprojT);
    flash_attn_mfma<<<512, 256, 0, stream>>>(userv, itemv, Ub, Ib, vprojT,
                                             po, pm, pl);
    merge_halves<<<1024, 256, 0, stream>>>(po, pm, pl, out);
}